// Round 12
// baseline (54.230 us; speedup 1.0000x reference)
//
#include <hip/hip_runtime.h>

#define BN 4096
#define SZ 2048
#define HIDN 128
#define NT 8
#define PADROWS 4384             // 4096 + 9*32 padding
#define PADTILES (PADROWS / 16)  // 274

typedef __bf16 bf16_t;
typedef bf16_t bf16x4 __attribute__((ext_vector_type(4)));
typedef bf16_t bf16x8 __attribute__((ext_vector_type(8)));
typedef float f32x4 __attribute__((ext_vector_type(4)));

__device__ inline bf16_t f2b(float f) {
    unsigned u = __builtin_bit_cast(unsigned, f);
    unsigned short s = (unsigned short)((u + 0x7fffu + ((u >> 16) & 1u)) >> 16);
    return __builtin_bit_cast(bf16_t, s);
}

// ws layout (bytes):
//   idxb  int[PADROWS] @0          (17536 B)
//   meta  int[64]      @17664      [0..8]=cnt, [16..25]=padded offs
//   (unused)           @17920
//   HbP   bf16 frag    @18560      [rt(274)][kf(4)][lane(64)][8]  (~1.1 MB)
//   WdP   bf16 frag    @1140864    [t][hf(8)][kt(64)][lane][8]    (4 MB)
//   WuP   bf16 frag    @5335168    [t][cf(128)][kf(4)][lane][8]   (4 MB)

// ---- prep: blocks 0..511 pack Wd; blocks 512..527 self-contained scatter ----
__global__ __launch_bounds__(256) void k_prep(const float* __restrict__ Wd,
                                              const int* __restrict__ task,
                                              bf16_t* __restrict__ WdP,
                                              int* __restrict__ meta,
                                              int* __restrict__ idxb) {
    int bid = blockIdx.x, tid = threadIdx.x;
    if (bid >= 512) {  // ---- scatter block blk: full hist locally + own slice ----
        __shared__ int c16s[16][9], tot[9], pre9[9], off[10], wv[4][9], sflag;
        int blk = bid - 512;
        int lane = tid & 63, w = tid >> 6;
        if (tid < 64) {
            int v = task[2 * tid + 1];
            bool ok = (v == 0 || v == -1);   // int64 detection via sign-ext words
            unsigned long long m = __ballot(ok);
            if (tid == 0) sflag = (m == ~0ull) ? 1 : 0;
        }
        __syncthreads();
        int f = sflag;
        int mybk = 0, myrank = 0, myprew = 0;
        for (int s = 0; s < 16; s++) {
            int item = s * 256 + tid;
            int tv = f ? task[2 * item] : task[item];
            int bk = (tv < 0) ? 8 : (tv > 7 ? 7 : tv);
            unsigned long long mymask = 0;
#pragma unroll
            for (int bu = 0; bu < 9; bu++) {
                unsigned long long m = __ballot(bk == bu);
                if (lane == 0) wv[w][bu] = (int)__popcll(m);
                if (bk == bu) mymask = m;
            }
            __syncthreads();   // wv stable
            if (s == blk) {
                mybk = bk;
                myrank = (int)__popcll(mymask & ((1ull << lane) - 1ull));
                myprew = 0;
                for (int ww = 0; ww < w; ww++) myprew += wv[ww][bk];
            }
            if (tid < 9) c16s[s][tid] = wv[0][tid] + wv[1][tid] + wv[2][tid] + wv[3][tid];
            __syncthreads();   // before wv overwritten
        }
        if (tid < 9) {
            int t = 0;
#pragma unroll
            for (int s = 0; s < 16; s++) t += c16s[s][tid];
            tot[tid] = t;
            int p = 0;
            for (int s = 0; s < blk; s++) p += c16s[s][tid];
            pre9[tid] = p;
        }
        __syncthreads();
        if (tid == 0) {
            int s = 0;
            for (int i = 0; i < 9; i++) { off[i] = s; s += (tot[i] + 31) & ~31; }
            off[9] = s;
        }
        __syncthreads();
        idxb[off[mybk] + pre9[mybk] + myprew + myrank] = blk * 256 + tid;
        if (blk == 0) {
            if (tid < 9) meta[tid] = tot[tid];
            if (tid >= 16 && tid < 26) meta[tid] = off[tid - 16];
        }
        return;
    }
    // ---- Wd pack (fp32 -> bf16 fragment layout) ----
    __shared__ float tile[32][132];
    int t = bid >> 6, kt = bid & 63;
    const float* src = Wd + ((size_t)t * SZ + kt * 32) * HIDN;
    bf16_t* dst = WdP + ((size_t)(t * 8) * 64 + kt) * 512;
#pragma unroll
    for (int i = 0; i < 4; i++) {
        int row = (tid >> 5) + 8 * i, quad = tid & 31;
        f32x4 v = *(const f32x4*)(src + (size_t)row * HIDN + quad * 4);
        tile[row][quad * 4 + 0] = v.x; tile[row][quad * 4 + 1] = v.y;
        tile[row][quad * 4 + 2] = v.z; tile[row][quad * 4 + 3] = v.w;
    }
    __syncthreads();
    int w = tid >> 6, lane = tid & 63, lr = lane & 15, lq = lane >> 4;
#pragma unroll
    for (int ii = 0; ii < 2; ii++) {
        int hf = w * 2 + ii;
        bf16x8 o;
#pragma unroll
        for (int j = 0; j < 8; j++) {
            int kloc = (j < 4) ? (4 * lq + j) : (16 + 4 * lq + j - 4);
            o[j] = f2b(tile[kloc][hf * 16 + lr]);
        }
        *(bf16x8*)(dst + (size_t)hf * 64 * 512 + lane * 8) = o;
    }
}

// ---- GEMM1 fused (h-split x2, dual-acc) + Wu-pack tail ----
// bid<4096: t = bid&7, hh = (bid>>3)&1 (64-h half), tile = bid>>4 (16 rows)
// bid>=4096: Wu pack (512 blocks) runs concurrently on idle CUs
__global__ __launch_bounds__(256) void k_gemm1(const float* __restrict__ x,
                                               const float* __restrict__ Wu,
                                               const bf16_t* __restrict__ WdP,
                                               bf16_t* __restrict__ WuP,
                                               const float* __restrict__ bd,
                                               const int* __restrict__ idxb,
                                               const int* __restrict__ meta,
                                               bf16_t* __restrict__ HbP) {
    int bid = blockIdx.x;
    int tid = threadIdx.x, lane = tid & 63, w = tid >> 6;
    int lr = lane & 15, lq = lane >> 4;
    if (bid >= 4096) {  // ---- Wu pack ----
        __shared__ float tile[32][132];
        int lb = bid - 4096;
        int t = lb >> 6, rem = lb & 63;
        int kf = rem >> 4, cch = rem & 15;
        const float* src = Wu + ((size_t)t * HIDN + kf * 32) * SZ + cch * 128;
        bf16_t* dst = WuP + ((size_t)(t * 128 + cch * 8) * 4 + kf) * 512;
#pragma unroll
        for (int i = 0; i < 4; i++) {
            int row = (tid >> 5) + 8 * i, quad = tid & 31;
            f32x4 v = *(const f32x4*)(src + (size_t)row * SZ + quad * 4);
            tile[row][quad * 4 + 0] = v.x; tile[row][quad * 4 + 1] = v.y;
            tile[row][quad * 4 + 2] = v.z; tile[row][quad * 4 + 3] = v.w;
        }
        __syncthreads();
#pragma unroll
        for (int ii = 0; ii < 2; ii++) {
            int hf = w * 2 + ii;
            bf16x8 o;
#pragma unroll
            for (int j = 0; j < 8; j++) {
                int kloc = (j < 4) ? (4 * lq + j) : (16 + 4 * lq + j - 4);
                o[j] = f2b(tile[kloc][hf * 16 + lr]);
            }
            *(bf16x8*)(dst + (size_t)hf * 4 * 512 + lane * 8) = o;
        }
        return;
    }
    int t = bid & 7, hh = (bid >> 3) & 1, tile = bid >> 4;
    int n = meta[t];
    int r0 = tile * 16;
    if (r0 >= n) return;
    int base = meta[16 + t];

    __shared__ int sg[16];
    __shared__ bf16_t xl[2][16][260];   // stride 260: <=2-way conflicts
    __shared__ bf16_t hl[16][68];       // local 64 h + pad
    if (tid < 16) {
        int r = r0 + tid;
        sg[tid] = idxb[base + (r < n ? r : n - 1)];
    }
    __syncthreads();

    // stage chunk 0: wave w loads rows 4w..4w+3, 256 f32 each, coalesced
    f32x4 pre[4];
#pragma unroll
    for (int rr = 0; rr < 4; rr++)
        pre[rr] = *(const f32x4*)(x + (size_t)sg[w * 4 + rr] * SZ + lane * 4);
#pragma unroll
    for (int rr = 0; rr < 4; rr++) {
        bf16x4 v = {f2b(pre[rr].x), f2b(pre[rr].y), f2b(pre[rr].z), f2b(pre[rr].w)};
        *(bf16x4*)(&xl[0][w * 4 + rr][lane * 4]) = v;
    }
    __syncthreads();

    // wave w computes hf = hh*4 + w; dual accumulators break the dep chain
    const bf16_t* wb = WdP + ((size_t)(t * 8 + hh * 4 + w) * 64) * 512 + lane * 8;
    f32x4 acc0 = {}, acc1 = {};
    for (int c = 0; c < 8; c++) {
        int cur = c & 1;
        if (c < 7) {
#pragma unroll
            for (int rr = 0; rr < 4; rr++)
                pre[rr] = *(const f32x4*)(x + (size_t)sg[w * 4 + rr] * SZ +
                                          (c + 1) * 256 + lane * 4);
        }
#pragma unroll
        for (int k8 = 0; k8 < 8; k8++) {
            int kf = c * 8 + k8;
            bf16x4 alo = *(const bf16x4*)(&xl[cur][lr][k8 * 32 + 4 * lq]);
            bf16x4 ahi = *(const bf16x4*)(&xl[cur][lr][k8 * 32 + 16 + 4 * lq]);
            bf16x8 a;
            a[0] = alo[0]; a[1] = alo[1]; a[2] = alo[2]; a[3] = alo[3];
            a[4] = ahi[0]; a[5] = ahi[1]; a[6] = ahi[2]; a[7] = ahi[3];
            bf16x8 b = *(const bf16x8*)(wb + (size_t)kf * 512);
            if (k8 & 1)
                acc1 = __builtin_amdgcn_mfma_f32_16x16x32_bf16(a, b, acc1, 0, 0, 0);
            else
                acc0 = __builtin_amdgcn_mfma_f32_16x16x32_bf16(a, b, acc0, 0, 0, 0);
        }
        if (c < 7) {
#pragma unroll
            for (int rr = 0; rr < 4; rr++) {
                bf16x4 v = {f2b(pre[rr].x), f2b(pre[rr].y), f2b(pre[rr].z), f2b(pre[rr].w)};
                *(bf16x4*)(&xl[cur ^ 1][w * 4 + rr][lane * 4]) = v;
            }
        }
        __syncthreads();
    }
    f32x4 acc = acc0 + acc1;

    // bias + silu -> hl (local h' = w*16+lr)
    {
        float bb = bd[t * HIDN + hh * 64 + w * 16 + lr];
#pragma unroll
        for (int reg = 0; reg < 4; reg++) {
            float v = acc[reg] + bb;
            hl[4 * lq + reg][w * 16 + lr] = f2b(v / (1.f + __expf(-v)));
        }
    }
    __syncthreads();
    // pack 2 kf slices (waves 0,1): global kf = hh*2 + s
    if (w < 2) {
        int rt = (base + r0) >> 4;
        bf16x8 o;
#pragma unroll
        for (int j = 0; j < 8; j++) {
            int k = w * 32 + ((j < 4) ? (4 * lq + j) : (16 + 4 * lq + j - 4));
            o[j] = hl[lr][k];
        }
        *(bf16x8*)(HbP + ((size_t)(rt * 4 + hh * 2 + w) * 64 + lane) * 8) = o;
    }
}

// ---- GEMM2 + residual + passthrough tail ----
// bid<16384: t = bid&7, tile = (bid>>3)&127 (32 rows), cchunk = bid>>10 (128 cols)
// bid>=16384: passthrough (bucket 8)
__global__ __launch_bounds__(256) void k_gemm2(const float* __restrict__ x,
                                               const bf16_t* __restrict__ WuP,
                                               const float* __restrict__ bu,
                                               const bf16_t* __restrict__ HbP,
                                               const int* __restrict__ idxb,
                                               const int* __restrict__ meta,
                                               float* __restrict__ out) {
    int bid = blockIdx.x;
    int tid = threadIdx.x;
    if (bid >= 16384) {
        int pb = bid - 16384;
        int n8 = meta[8];
        int tile = pb & 127, half = pb >> 7;
        int r0 = tile * 32;
        if (r0 >= n8) return;
        int base8 = meta[16 + 8];
        int row = tid >> 3, cq = tid & 7;
        int r = r0 + row;
        if (r < n8) {
            int g = idxb[base8 + r];
            const f32x4* xs = (const f32x4*)(x + (size_t)g * SZ + half * 256) + cq;
            f32x4* os = (f32x4*)(out + (size_t)g * SZ + half * 256) + cq;
#pragma unroll
            for (int j = 0; j < 8; j++) __builtin_nontemporal_store(xs[j * 8], &os[j * 8]);
        }
        return;
    }
    int t = bid & 7, tile = (bid >> 3) & 127, cchunk = bid >> 10;
    int n = meta[t];
    int r0 = tile * 32;
    if (r0 >= n) return;
    int base = meta[16 + t];
    int lane = tid & 63, w = tid >> 6;
    int wr = w & 1, wc = w >> 1, lr = lane & 15, lq = lane >> 4;

    int rt = (base + r0) / 16 + wr;           // base is 32-aligned
    const bf16_t* ap = HbP + (size_t)rt * 4 * 512 + lane * 8;
    bf16x8 a[4];
#pragma unroll
    for (int kf = 0; kf < 4; kf++) a[kf] = *(const bf16x8*)(ap + kf * 512);

    const bf16_t* bp = WuP + ((size_t)(t * 128 + cchunk * 8 + wc * 4) * 4) * 512 + lane * 8;
    f32x4 acc[4] = {};
#pragma unroll
    for (int cf = 0; cf < 4; cf++) {
#pragma unroll
        for (int kf = 0; kf < 4; kf++) {
            bf16x8 b = *(const bf16x8*)(bp + (size_t)(cf * 4 + kf) * 512);
            acc[cf] = __builtin_amdgcn_mfma_f32_16x16x32_bf16(a[kf], b, acc[cf], 0, 0, 0);
        }
    }

    int gr[4];
#pragma unroll
    for (int reg = 0; reg < 4; reg++) {
        int r = r0 + wr * 16 + 4 * lq + reg;
        gr[reg] = (r < n) ? idxb[base + r] : -1;
    }
#pragma unroll
    for (int cf = 0; cf < 4; cf++) {
        int c = cchunk * 128 + wc * 64 + cf * 16 + lr;
        float bb = bu[t * SZ + c];
#pragma unroll
        for (int reg = 0; reg < 4; reg++) {
            if (gr[reg] >= 0) {
                size_t o = (size_t)gr[reg] * SZ + c;
                __builtin_nontemporal_store(x[o] + acc[cf][reg] + bb, &out[o]);
            }
        }
    }
}

extern "C" void kernel_launch(void* const* d_in, const int* in_sizes, int n_in,
                              void* d_out, int out_size, void* d_ws, size_t ws_size,
                              hipStream_t stream) {
    const float* x  = (const float*)d_in[0];
    const float* Wd = (const float*)d_in[1];
    const float* bd = (const float*)d_in[2];
    const float* Wu = (const float*)d_in[3];
    const float* bu = (const float*)d_in[4];
    const int* task = (const int*)d_in[5];
    float* out = (float*)d_out;

    char* ws = (char*)d_ws;
    int* idxb    = (int*)ws;
    int* meta    = (int*)(ws + 17664);
    bf16_t* HbP  = (bf16_t*)(ws + 18560);
    bf16_t* WdP  = (bf16_t*)(ws + 1140864);
    bf16_t* WuP  = (bf16_t*)(ws + 5335168);

    k_prep<<<528, 256, 0, stream>>>(Wd, task, WdP, meta, idxb);
    k_gemm1<<<4096 + 512, 256, 0, stream>>>(x, Wu, WdP, WuP, bd, idxb, meta, HbP);
    k_gemm2<<<16384 + 1024, 256, 0, stream>>>(x, WuP, bu, HbP, idxb, meta, out);
}

// Round 13
// 48.169 us; speedup vs baseline: 1.1258x; 1.1258x over previous
//
#include <hip/hip_runtime.h>

#define BN 4096
#define SZ 2048
#define HIDN 128
#define NT 8
#define PADROWS 4384             // 4096 + 9*32 padding
#define PADTILES (PADROWS / 16)  // 274

typedef __bf16 bf16_t;
typedef bf16_t bf16x4 __attribute__((ext_vector_type(4)));
typedef bf16_t bf16x8 __attribute__((ext_vector_type(8)));
typedef float f32x4 __attribute__((ext_vector_type(4)));

__device__ inline bf16_t f2b(float f) {
    unsigned u = __builtin_bit_cast(unsigned, f);
    unsigned short s = (unsigned short)((u + 0x7fffu + ((u >> 16) & 1u)) >> 16);
    return __builtin_bit_cast(bf16_t, s);
}

// ws layout (bytes):
//   idxb  int[PADROWS] @0          (17536 B)
//   meta  int[64]      @17664      [0..8]=cnt, [16..25]=padded offs
//   cnt16 int[16*9]    @17920      per-hist-block bucket counts
//   HbP   bf16 frag    @18560      [rt(274)][kf(4)][lane(64)][8]  (~1.1 MB)
//   WdP   bf16 frag    @1140864    [t][hf(8)][kt(64)][lane][8]    (4 MB)
//   WuP   bf16 frag    @5335168    [t][cf(128)][kf(4)][lane][8]   (4 MB)

__device__ inline int detect_i64(const int* task, int tid, int* sflag) {
    // sample 64 odd words; int64 -> all are 0/-1 sign extensions
    if (tid < 64) {
        int v = task[2 * tid + 1];
        bool ok = (v == 0 || v == -1);
        unsigned long long m = __ballot(ok);
        if (tid == 0) *sflag = (m == ~0ull) ? 1 : 0;
    }
    return 0;
}

// ---- prep: blocks 0..511 pack Wd; blocks 512..527 histogram ----
__global__ __launch_bounds__(256) void k_prep(const float* __restrict__ Wd,
                                              const int* __restrict__ task,
                                              bf16_t* __restrict__ WdP,
                                              int* __restrict__ cnt16g) {
    int bid = blockIdx.x, tid = threadIdx.x;
    __shared__ int wv[4][9], sflag;
    if (bid >= 512) {  // ---- histogram: 16 blocks, 256 items each ----
        int blk = bid - 512;
        int lane = tid & 63, w = tid >> 6;
        detect_i64(task, tid, &sflag);
        __syncthreads();
        int f = sflag;
        int item = blk * 256 + tid;
        int tv = f ? task[2 * item] : task[item];
        int bk = (tv < 0) ? 8 : (tv > 7 ? 7 : tv);
#pragma unroll
        for (int bu = 0; bu < 9; bu++) {
            unsigned long long m = __ballot(bk == bu);
            if (lane == 0) wv[w][bu] = (int)__popcll(m);
        }
        __syncthreads();
        if (tid < 9) {
            int s = 0;
#pragma unroll
            for (int ww = 0; ww < 4; ww++) s += wv[ww][tid];
            cnt16g[blk * 9 + tid] = s;
        }
        return;
    }
    // ---- Wd pack (fp32 -> bf16 fragment layout) ----
    __shared__ float tile[32][132];
    int t = bid >> 6, kt = bid & 63;
    const float* src = Wd + ((size_t)t * SZ + kt * 32) * HIDN;
    bf16_t* dst = WdP + ((size_t)(t * 8) * 64 + kt) * 512;
#pragma unroll
    for (int i = 0; i < 4; i++) {
        int row = (tid >> 5) + 8 * i, quad = tid & 31;
        f32x4 v = *(const f32x4*)(src + (size_t)row * HIDN + quad * 4);
        tile[row][quad * 4 + 0] = v.x; tile[row][quad * 4 + 1] = v.y;
        tile[row][quad * 4 + 2] = v.z; tile[row][quad * 4 + 3] = v.w;
    }
    __syncthreads();
    int w = tid >> 6, lane = tid & 63, lr = lane & 15, lq = lane >> 4;
#pragma unroll
    for (int ii = 0; ii < 2; ii++) {
        int hf = w * 2 + ii;
        bf16x8 o;
#pragma unroll
        for (int j = 0; j < 8; j++) {
            int kloc = (j < 4) ? (4 * lq + j) : (16 + 4 * lq + j - 4);
            o[j] = f2b(tile[kloc][hf * 16 + lr]);
        }
        *(bf16x8*)(dst + (size_t)hf * 64 * 512 + lane * 8) = o;
    }
}

// ---- scatter: 16 blocks; deterministic positions from cnt16 (no atomics) ----
__global__ __launch_bounds__(256) void k_scatter(const int* __restrict__ task,
                                                 const int* __restrict__ cnt16g,
                                                 int* __restrict__ meta,
                                                 int* __restrict__ idxb) {
    __shared__ int c16s[16][9], tot[9], pre9[9], off[10], wv[4][9], sflag;
    int tid = threadIdx.x, lane = tid & 63, w = tid >> 6, blk = blockIdx.x;
    detect_i64(task, tid, &sflag);
    if (tid < 144) ((int*)c16s)[tid] = cnt16g[tid];
    __syncthreads();
    int f = sflag;
    int item = blk * 256 + tid;
    int tv = f ? task[2 * item] : task[item];
    int bk = (tv < 0) ? 8 : (tv > 7 ? 7 : tv);
    unsigned long long mymask = 0;
#pragma unroll
    for (int bu = 0; bu < 9; bu++) {
        unsigned long long m = __ballot(bk == bu);
        if (lane == 0) wv[w][bu] = (int)__popcll(m);
        if (bk == bu) mymask = m;
    }
    int rank = (int)__popcll(mymask & ((1ull << lane) - 1ull));
    __syncthreads();
    if (tid < 9) {
        int t = 0;
#pragma unroll
        for (int b = 0; b < 16; b++) t += c16s[b][tid];
        tot[tid] = t;
        int p = 0;
        for (int b = 0; b < blk; b++) p += c16s[b][tid];
        pre9[tid] = p;
        int s = 0;
#pragma unroll
        for (int ww = 0; ww < 4; ww++) { int q = wv[ww][tid]; wv[ww][tid] = s; s += q; }
    }
    __syncthreads();
    if (tid == 0) {
        int s = 0;
        for (int i = 0; i < 9; i++) { off[i] = s; s += (tot[i] + 31) & ~31; }
        off[9] = s;
    }
    __syncthreads();
    int pos = off[bk] + pre9[bk] + wv[w][bk] + rank;
    idxb[pos] = item;
    if (blk == 0) {
        if (tid < 9) meta[tid] = tot[tid];
        if (tid >= 16 && tid < 26) meta[tid] = off[tid - 16];
    }
}

// ---- GEMM1 fused, 512 threads = 4 hf-waves x 2 K-groups + Wu-pack tail ----
// bid<4096: t = bid&7, hh = (bid>>3)&1 (64-h half), tile = bid>>4 (16 rows)
// bid>=4096: Wu pack, 2 units per block (512 thr = 2 halves)
__global__ __launch_bounds__(512) void k_gemm1(const float* __restrict__ x,
                                               const float* __restrict__ Wu,
                                               const bf16_t* __restrict__ WdP,
                                               bf16_t* __restrict__ WuP,
                                               const float* __restrict__ bd,
                                               const int* __restrict__ idxb,
                                               const int* __restrict__ meta,
                                               bf16_t* __restrict__ HbP) {
    __shared__ __align__(16) char smem[40192];
    int bid = blockIdx.x;
    int tid = threadIdx.x;
    if (bid >= 4096) {  // ---- Wu pack: 2 units/block ----
        float (*tile2)[32][132] = (float (*)[32][132])smem;
        int half = tid >> 8, t256 = tid & 255;
        int lb = (bid - 4096) * 2 + half;
        int t = lb >> 6, rem = lb & 63;
        int kf = rem >> 4, cch = rem & 15;
        const float* src = Wu + ((size_t)t * HIDN + kf * 32) * SZ + cch * 128;
        bf16_t* dst = WuP + ((size_t)(t * 128 + cch * 8) * 4 + kf) * 512;
#pragma unroll
        for (int i = 0; i < 4; i++) {
            int row = (t256 >> 5) + 8 * i, quad = t256 & 31;
            f32x4 v = *(const f32x4*)(src + (size_t)row * SZ + quad * 4);
            tile2[half][row][quad * 4 + 0] = v.x; tile2[half][row][quad * 4 + 1] = v.y;
            tile2[half][row][quad * 4 + 2] = v.z; tile2[half][row][quad * 4 + 3] = v.w;
        }
        __syncthreads();
        int w2 = t256 >> 6, lane2 = t256 & 63, lr2 = lane2 & 15, lq2 = lane2 >> 4;
#pragma unroll
        for (int ii = 0; ii < 2; ii++) {
            int hf2 = w2 * 2 + ii;
            bf16x8 o;
#pragma unroll
            for (int j = 0; j < 8; j++) {
                int kloc = (j < 4) ? (4 * lq2 + j) : (16 + 4 * lq2 + j - 4);
                o[j] = f2b(tile2[half][kloc][hf2 * 16 + lr2]);
            }
            *(bf16x8*)(dst + (size_t)hf2 * 4 * 512 + lane2 * 8) = o;
        }
        return;
    }
    int t = bid & 7, hh = (bid >> 3) & 1, tile = bid >> 4;
    int n = meta[t];
    int r0 = tile * 16;
    if (r0 >= n) return;
    int base = meta[16 + t];
    int lane = tid & 63, w16 = tid >> 6;
    int hf = w16 & 3, kg = w16 >> 2;
    int lr = lane & 15, lq = lane >> 4;

    int* sg = (int*)smem;                                              // 64 B
    bf16_t (*xl)[2][16][260] = (bf16_t (*)[2][16][260])(smem + 64);    // 33280 B
    bf16_t (*hl)[68] = (bf16_t (*)[68])(smem + 33344);                 // 2176 B
    float (*red)[68] = (float (*)[68])(smem + 35520);                  // 4352 B

    if (tid < 16) {
        int r = r0 + tid;
        sg[tid] = idxb[base + (r < n ? r : n - 1)];
    }
    __syncthreads();

    // stage chunk 0 of this kg: wave (hf,kg) loads rows hf*4..hf*4+3, coalesced
    f32x4 pre[4];
#pragma unroll
    for (int rr = 0; rr < 4; rr++)
        pre[rr] = *(const f32x4*)(x + (size_t)sg[hf * 4 + rr] * SZ + kg * 1024 + lane * 4);
#pragma unroll
    for (int rr = 0; rr < 4; rr++) {
        bf16x4 v = {f2b(pre[rr].x), f2b(pre[rr].y), f2b(pre[rr].z), f2b(pre[rr].w)};
        *(bf16x4*)(&xl[kg][0][hf * 4 + rr][lane * 4]) = v;
    }
    __syncthreads();

    // wave (hf,kg): h-col block hf, K-range [kg*1024, kg*1024+1024)
    const bf16_t* wb = WdP + ((size_t)(t * 8 + hh * 4 + hf) * 64) * 512 + lane * 8;
    f32x4 acc = {};
    for (int c = 0; c < 4; c++) {
        int cur = c & 1;
        if (c < 3) {
#pragma unroll
            for (int rr = 0; rr < 4; rr++)
                pre[rr] = *(const f32x4*)(x + (size_t)sg[hf * 4 + rr] * SZ +
                                          kg * 1024 + (c + 1) * 256 + lane * 4);
        }
#pragma unroll
        for (int k8 = 0; k8 < 8; k8++) {
            int kf = kg * 32 + c * 8 + k8;
            bf16x4 alo = *(const bf16x4*)(&xl[kg][cur][lr][k8 * 32 + 4 * lq]);
            bf16x4 ahi = *(const bf16x4*)(&xl[kg][cur][lr][k8 * 32 + 16 + 4 * lq]);
            bf16x8 a;
            a[0] = alo[0]; a[1] = alo[1]; a[2] = alo[2]; a[3] = alo[3];
            a[4] = ahi[0]; a[5] = ahi[1]; a[6] = ahi[2]; a[7] = ahi[3];
            bf16x8 b = *(const bf16x8*)(wb + (size_t)kf * 512);
            acc = __builtin_amdgcn_mfma_f32_16x16x32_bf16(a, b, acc, 0, 0, 0);
        }
        if (c < 3) {
#pragma unroll
            for (int rr = 0; rr < 4; rr++) {
                bf16x4 v = {f2b(pre[rr].x), f2b(pre[rr].y), f2b(pre[rr].z), f2b(pre[rr].w)};
                *(bf16x4*)(&xl[kg][cur ^ 1][hf * 4 + rr][lane * 4]) = v;
            }
        }
        __syncthreads();
    }

    // K-group reduce: kg1 writes partials, kg0 adds + bias + silu -> hl
    if (kg == 1) {
#pragma unroll
        for (int reg = 0; reg < 4; reg++)
            red[4 * lq + reg][hf * 16 + lr] = acc[reg];
    }
    __syncthreads();
    if (kg == 0) {
        float bb = bd[t * HIDN + hh * 64 + hf * 16 + lr];
#pragma unroll
        for (int reg = 0; reg < 4; reg++) {
            float v = acc[reg] + red[4 * lq + reg][hf * 16 + lr] + bb;
            hl[4 * lq + reg][hf * 16 + lr] = f2b(v / (1.f + __expf(-v)));
        }
    }
    __syncthreads();
    // pack 2 kf slices (kg0, hf<2): global kf = hh*2 + hf
    if (kg == 0 && hf < 2) {
        int rt = (base + r0) >> 4;
        bf16x8 o;
#pragma unroll
        for (int j = 0; j < 8; j++) {
            int k = hf * 32 + ((j < 4) ? (4 * lq + j) : (16 + 4 * lq + j - 4));
            o[j] = hl[lr][k];
        }
        *(bf16x8*)(HbP + ((size_t)(rt * 4 + hh * 2 + hf) * 64 + lane) * 8) = o;
    }
}

// ---- GEMM2 + residual + passthrough tail ----
// bid<16384: t = bid&7, tile = (bid>>3)&127 (32 rows), cchunk = bid>>10 (128 cols)
// bid>=16384: passthrough (bucket 8)
__global__ __launch_bounds__(256) void k_gemm2(const float* __restrict__ x,
                                               const bf16_t* __restrict__ WuP,
                                               const float* __restrict__ bu,
                                               const bf16_t* __restrict__ HbP,
                                               const int* __restrict__ idxb,
                                               const int* __restrict__ meta,
                                               float* __restrict__ out) {
    int bid = blockIdx.x;
    int tid = threadIdx.x;
    if (bid >= 16384) {
        int pb = bid - 16384;
        int n8 = meta[8];
        int tile = pb & 127, half = pb >> 7;
        int r0 = tile * 32;
        if (r0 >= n8) return;
        int base8 = meta[16 + 8];
        int row = tid >> 3, cq = tid & 7;
        int r = r0 + row;
        if (r < n8) {
            int g = idxb[base8 + r];
            const f32x4* xs = (const f32x4*)(x + (size_t)g * SZ + half * 256) + cq;
            f32x4* os = (f32x4*)(out + (size_t)g * SZ + half * 256) + cq;
#pragma unroll
            for (int j = 0; j < 8; j++) __builtin_nontemporal_store(xs[j * 8], &os[j * 8]);
        }
        return;
    }
    int t = bid & 7, tile = (bid >> 3) & 127, cchunk = bid >> 10;
    int n = meta[t];
    int r0 = tile * 32;
    if (r0 >= n) return;
    int base = meta[16 + t];
    int lane = tid & 63, w = tid >> 6;
    int wr = w & 1, wc = w >> 1, lr = lane & 15, lq = lane >> 4;

    int rt = (base + r0) / 16 + wr;           // base is 32-aligned
    const bf16_t* ap = HbP + (size_t)rt * 4 * 512 + lane * 8;
    bf16x8 a[4];
#pragma unroll
    for (int kf = 0; kf < 4; kf++) a[kf] = *(const bf16x8*)(ap + kf * 512);

    const bf16_t* bp = WuP + ((size_t)(t * 128 + cchunk * 8 + wc * 4) * 4) * 512 + lane * 8;
    f32x4 acc[4] = {};
#pragma unroll
    for (int cf = 0; cf < 4; cf++) {
#pragma unroll
        for (int kf = 0; kf < 4; kf++) {
            bf16x8 b = *(const bf16x8*)(bp + (size_t)(cf * 4 + kf) * 512);
            acc[cf] = __builtin_amdgcn_mfma_f32_16x16x32_bf16(a[kf], b, acc[cf], 0, 0, 0);
        }
    }

    int gr[4];
#pragma unroll
    for (int reg = 0; reg < 4; reg++) {
        int r = r0 + wr * 16 + 4 * lq + reg;
        gr[reg] = (r < n) ? idxb[base + r] : -1;
    }
#pragma unroll
    for (int cf = 0; cf < 4; cf++) {
        int c = cchunk * 128 + wc * 64 + cf * 16 + lr;
        float bb = bu[t * SZ + c];
#pragma unroll
        for (int reg = 0; reg < 4; reg++) {
            if (gr[reg] >= 0) {
                size_t o = (size_t)gr[reg] * SZ + c;
                __builtin_nontemporal_store(x[o] + acc[cf][reg] + bb, &out[o]);
            }
        }
    }
}

extern "C" void kernel_launch(void* const* d_in, const int* in_sizes, int n_in,
                              void* d_out, int out_size, void* d_ws, size_t ws_size,
                              hipStream_t stream) {
    const float* x  = (const float*)d_in[0];
    const float* Wd = (const float*)d_in[1];
    const float* bd = (const float*)d_in[2];
    const float* Wu = (const float*)d_in[3];
    const float* bu = (const float*)d_in[4];
    const int* task = (const int*)d_in[5];
    float* out = (float*)d_out;

    char* ws = (char*)d_ws;
    int* idxb    = (int*)ws;
    int* meta    = (int*)(ws + 17664);
    int* cnt16   = (int*)(ws + 17920);
    bf16_t* HbP  = (bf16_t*)(ws + 18560);
    bf16_t* WdP  = (bf16_t*)(ws + 1140864);
    bf16_t* WuP  = (bf16_t*)(ws + 5335168);

    k_prep<<<528, 256, 0, stream>>>(Wd, task, WdP, cnt16);
    k_scatter<<<16, 256, 0, stream>>>(task, cnt16, meta, idxb);
    k_gemm1<<<4096 + 256, 512, 0, stream>>>(x, Wu, WdP, WuP, bd, idxb, meta, HbP);
    k_gemm2<<<16384 + 1024, 256, 0, stream>>>(x, WuP, bu, HbP, idxb, meta, out);
}